// Round 5
// baseline (212.357 us; speedup 1.0000x reference)
//
#include <hip/hip_runtime.h>
#include <hip/hip_bf16.h>
#include <hip/hip_cooperative_groups.h>

namespace cg = cooperative_groups;

// CIF (Continuous Integrate-and-Fire)
// B=16, T=2048, D=512, threshold=1.0
// Outputs (flat in d_out, float32): out[B*T*D], out_len[B] (as float), qloss[1]
//
// Structure (R5): ONE cooperative kernel, 512 blocks x 256 threads (2/CU).
//   Phase 1: blocks 0..15 scan their batch (f64 cumsum -> fires/weights);
//            blocks 16..511 zero-stream rows s in [512,2048) (48 MB, always
//            zero since out_len <= tgt_len <= 511).
//   grid.sync()
//   Phase 2: 2048 waves gather the 8192 candidate rows (4 rows per wave,
//            one row per wave at a time, 64 lanes x 2 f4 = 512 floats).

constexpr int Bc = 16;
constexpr int Tc = 2048;
constexpr int Dc = 512;
constexpr int SMAX = 512;   // out_len <= tgt_len <= 511 (distinct integer Dq per fire)
constexpr int GRID = 512;

typedef float f4 __attribute__((ext_vector_type(4)));

__global__ __launch_bounds__(256) void cif_fused_kernel(
    const float* __restrict__ prob, const int* __restrict__ x_len,
    const int* __restrict__ tgt_len, float* __restrict__ wm,
    float* __restrict__ wl, int* __restrict__ seg_end,
    int* __restrict__ out_len, double* __restrict__ qloss,
    const f4* __restrict__ x4, f4* __restrict__ out4,
    float* __restrict__ out_tail)
{
    const int tid  = threadIdx.x;
    const int blk  = blockIdx.x;
    const int lane = tid & 63;
    const int wave = tid >> 6;           // 0..3
    constexpr int rs = Dc / 4;           // 128 f4 per row

    __shared__ double s_wave[4];
    __shared__ double s_bcast;
    __shared__ int    s_wavei[4];

    // ===================== Phase 1 =====================
    if (blk < Bc) {
        const int b = blk;
        const int xl = x_len[b];
        const double tgt = (double)tgt_len[b];

        // load + mask (f64)
        double p[8];
        double lsum = 0.0;
        const int t0 = tid * 8;
        #pragma unroll
        for (int i = 0; i < 8; ++i) {
            int t = t0 + i;
            float pv = prob[b * Tc + t];
            double v = (t < xl) ? (double)pv : 0.0;
            p[i] = v;
            lsum += v;
        }

        // block reduce -> sum_prob
        double wsum = lsum;
        #pragma unroll
        for (int off = 32; off > 0; off >>= 1) wsum += __shfl_down(wsum, off, 64);
        if (lane == 0) s_wave[wave] = wsum;
        __syncthreads();
        if (tid == 0) {
            double total = s_wave[0] + s_wave[1] + s_wave[2] + s_wave[3];
            s_bcast = total;
            qloss[b] = fabs(total - tgt);
        }
        __syncthreads();
        const double total = s_bcast;
        const double scale = tgt / total;

        // scale + thread-local inclusive scan
        double c[8];
        double run = 0.0;
        #pragma unroll
        for (int i = 0; i < 8; ++i) { p[i] *= scale; run += p[i]; c[i] = run; }

        // block scan of thread totals (inclusive within wave via shfl_up)
        double xs = run;
        #pragma unroll
        for (int off = 1; off < 64; off <<= 1) {
            double y = __shfl_up(xs, off, 64);
            if (lane >= off) xs += y;
        }
        __syncthreads();               // s_wave reads above are done
        if (lane == 63) s_wave[wave] = xs;
        __syncthreads();
        double woff = 0.0;
        #pragma unroll
        for (int w = 0; w < 4; ++w) if (w < wave) woff += s_wave[w];
        const double excl = woff + (xs - run);   // exclusive prefix of this thread

        // fire detection + weights
        int    fire[8];
        double wmv[8], wlv[8];
        int fcnt = 0;
        double Cprev = excl;
        #pragma unroll
        for (int i = 0; i < 8; ++i) {
            int t = t0 + i;
            double C  = excl + c[i];
            double Dq = floor(C);
            double Dp = floor(Cprev);
            bool f = (Dq != Dp) && (t < xl);
            fire[i] = f ? 1 : 0;
            fcnt += fire[i];
            wmv[i] = f ? (Dq - Cprev) : p[i];
            wlv[i] = f ? (C - Dq) : 0.0;
            Cprev = C;
        }

        // block exclusive scan of fire counts -> global fire index
        int fx = fcnt;
        #pragma unroll
        for (int off = 1; off < 64; off <<= 1) {
            int y = __shfl_up(fx, off, 64);
            if (lane >= off) fx += y;
        }
        if (lane == 63) s_wavei[wave] = fx;
        __syncthreads();
        int ioff = 0;
        #pragma unroll
        for (int w = 0; w < 4; ++w) if (w < wave) ioff += s_wavei[w];
        int k = ioff + (fx - fcnt);              // fires strictly before this thread
        if (tid == 255) out_len[b] = ioff + fx;  // total fires

        // store weights and fire positions
        #pragma unroll
        for (int i = 0; i < 8; ++i) {
            int t = t0 + i;
            wm[b * Tc + t] = (float)wmv[i];
            wl[b * Tc + t] = (float)wlv[i];
            if (fire[i]) { seg_end[b * Tc + k] = t; ++k; }
        }
        __threadfence();   // device-scope visibility before grid.sync
    } else {
        // ---- zero-stream rows [512,2048) of every batch ----
        const f4 z = {0.f, 0.f, 0.f, 0.f};
        const int nzb    = (int)gridDim.x - Bc;
        const int idx0   = (blk - Bc) * 256 + tid;
        const int stride = nzb * 256;
        constexpr int perBatch  = (Tc - SMAX) * rs;   // 196608 f4
        constexpr int batchStrd = Tc * rs;            // 262144 f4
        constexpr int skip      = SMAX * rs;          // 65536 f4
        constexpr int ZN        = Bc * perBatch;
        for (int j = idx0; j < ZN; j += stride) {
            int b   = j / perBatch;
            int off = j - b * perBatch;
            __builtin_nontemporal_store(z, &out4[(size_t)b * batchStrd + skip + off]);
        }
    }

    cg::this_grid().sync();

    // ===================== Phase 2 =====================
    // tail outputs
    if (blk == 0) {
        if (tid < Bc) out_tail[tid] = (float)out_len[tid];
        if (tid == Bc) {
            double q = 0.0;
            #pragma unroll
            for (int i = 0; i < Bc; ++i) q += qloss[i];
            out_tail[Bc] = (float)(q / (double)Bc);
        }
    }

    // gather: one candidate row per wave per pass
    const int waveId   = blk * 4 + wave;
    const int totWaves = (int)gridDim.x * 4;
    const int nRows    = Bc * SMAX;                 // 8192
    for (int row = waveId; row < nRows; row += totWaves) {
        const int b    = row >> 9;                  // row / SMAX
        const int s    = row & (SMAX - 1);
        const int base = b * Tc;

        f4 a0 = {0.f, 0.f, 0.f, 0.f};
        f4 a1 = a0;
        const int ol = out_len[b];
        if (s < ol) {
            const int tEnd = seg_end[base + s];
            const int tBeg = (s == 0) ? 0 : (seg_end[base + s - 1] + 1);
            const f4* xr = x4 + (size_t)base * rs;
            for (int t = tBeg; t <= tEnd; ++t) {
                float w = wm[base + t];
                const f4* xp = xr + (size_t)t * rs;
                a0 += w * xp[lane];
                a1 += w * xp[lane + 64];
            }
            // w_left: previous segment's terminating fire, or (row 0 only)
            // the reference's extra fire[0] add.
            int tl = -1;
            if (s > 0)          tl = tBeg - 1;
            else if (tEnd == 0) tl = 0;             // fire at t==0
            if (tl >= 0) {
                float w = wl[base + tl];
                const f4* xp = xr + (size_t)tl * rs;
                a0 += w * xp[lane];
                a1 += w * xp[lane + 64];
            }
        }
        f4* op = out4 + (size_t)(base + s) * rs;
        __builtin_nontemporal_store(a0, &op[lane]);
        __builtin_nontemporal_store(a1, &op[lane + 64]);
    }
}

extern "C" void kernel_launch(void* const* d_in, const int* in_sizes, int n_in,
                              void* d_out, int out_size, void* d_ws, size_t ws_size,
                              hipStream_t stream) {
    const float* x       = (const float*)d_in[0];
    const int*   x_len   = (const int*)d_in[1];
    const float* prob    = (const float*)d_in[2];
    const int*   tgt_len = (const int*)d_in[3];

    float* out = (float*)d_out;

    // workspace layout (8B-aligned first)
    char* ws = (char*)d_ws;
    double* qloss  = (double*)ws;                       // B doubles
    float*  wm     = (float*)(ws + 128);                // B*T floats
    float*  wl     = (float*)(ws + 128 + Bc*Tc*4);      // B*T floats
    int*    segend = (int*)  (ws + 128 + 2*Bc*Tc*4);    // B*T ints
    int*    olen   = (int*)  (ws + 128 + 3*Bc*Tc*4);    // B ints

    const f4* x4       = (const f4*)x;
    f4*       out4     = (f4*)out;
    float*    out_tail = out + (size_t)Bc * Tc * Dc;

    void* args[] = { (void*)&prob, (void*)&x_len, (void*)&tgt_len,
                     (void*)&wm, (void*)&wl, (void*)&segend, (void*)&olen,
                     (void*)&qloss, (void*)&x4, (void*)&out4, (void*)&out_tail };

    hipLaunchCooperativeKernel((const void*)cif_fused_kernel,
                               dim3(GRID), dim3(256), args, 0, stream);
}

// Round 6
// 119.781 us; speedup vs baseline: 1.7729x; 1.7729x over previous
//
#include <hip/hip_runtime.h>
#include <hip/hip_bf16.h>

// CIF (Continuous Integrate-and-Fire)
// B=16, T=2048, D=512, threshold=1.0
// Outputs (flat in d_out, float32): out[B*T*D], out_len[B] (as float), qloss[1]
//
// Structure (R6 = revert to R4, the best measured config):
//   kernel 1: 16 scan blocks (one per batch) + 240 zero-stream blocks filling
//             out rows s in [512,2048) (always zero since out_len<=511).
//   kernel 2: one 128-thread block per candidate row (s<512): segment gather.
// Measured calibration (R5): harness reset floor ~110 us inside the timed
// window; this structure's kernel portion ~10-15 us ~= 95 MB HBM bytes floor.

constexpr int Bc = 16;
constexpr int Tc = 2048;
constexpr int Dc = 512;
constexpr int SMAX = 512;   // out_len <= tgt_len <= 511 (distinct integer Dq per fire)

typedef float f4 __attribute__((ext_vector_type(4)));

constexpr int ZBLK = 240;                            // zero-stream blocks in kernel 1
constexpr int ZN   = Bc * (Tc - SMAX) * (Dc / 4);    // f4 elements in the zero region

// ---------------- Kernel 1: per-batch scan + zero-stream ----------------
__global__ __launch_bounds__(256) void cif_scan_kernel(
    const float* __restrict__ prob, const int* __restrict__ x_len,
    const int* __restrict__ tgt_len, float* __restrict__ wm,
    float* __restrict__ wl, int* __restrict__ seg_end,
    int* __restrict__ out_len, double* __restrict__ qloss,
    f4* __restrict__ out4)
{
    const int tid = threadIdx.x;

    if (blockIdx.x >= Bc) {
        // ---- zero-stream rows [512,2048) of every batch ----
        const f4 z = {0.f, 0.f, 0.f, 0.f};
        const int idx0   = (blockIdx.x - Bc) * 256 + tid;
        const int stride = ZBLK * 256;
        constexpr int perBatch   = (Tc - SMAX) * (Dc / 4);  // 196608 f4
        constexpr int batchStrd  = Tc * (Dc / 4);           // 262144 f4
        constexpr int skip       = SMAX * (Dc / 4);         // 65536 f4
        for (int j = idx0; j < ZN; j += stride) {
            int b   = j / perBatch;
            int off = j - b * perBatch;
            __builtin_nontemporal_store(z, &out4[(size_t)b * batchStrd + skip + off]);
        }
        return;
    }

    const int b    = blockIdx.x;
    const int lane = tid & 63;
    const int wave = tid >> 6;           // 0..3
    const int xl   = x_len[b];
    const double tgt = (double)tgt_len[b];

    __shared__ double s_wave[4];
    __shared__ double s_bcast;
    __shared__ int    s_wavei[4];

    // load + mask (f64)
    double p[8];
    double lsum = 0.0;
    const int t0 = tid * 8;
    #pragma unroll
    for (int i = 0; i < 8; ++i) {
        int t = t0 + i;
        float pv = prob[b * Tc + t];
        double v = (t < xl) ? (double)pv : 0.0;
        p[i] = v;
        lsum += v;
    }

    // block reduce -> sum_prob
    double wsum = lsum;
    #pragma unroll
    for (int off = 32; off > 0; off >>= 1) wsum += __shfl_down(wsum, off, 64);
    if (lane == 0) s_wave[wave] = wsum;
    __syncthreads();
    if (tid == 0) {
        double total = s_wave[0] + s_wave[1] + s_wave[2] + s_wave[3];
        s_bcast = total;
        qloss[b] = fabs(total - tgt);
    }
    __syncthreads();
    const double total = s_bcast;
    const double scale = tgt / total;

    // scale + thread-local inclusive scan
    double c[8];
    double run = 0.0;
    #pragma unroll
    for (int i = 0; i < 8; ++i) { p[i] *= scale; run += p[i]; c[i] = run; }

    // block scan of thread totals (inclusive within wave via shfl_up)
    double xs = run;
    #pragma unroll
    for (int off = 1; off < 64; off <<= 1) {
        double y = __shfl_up(xs, off, 64);
        if (lane >= off) xs += y;
    }
    __syncthreads();               // s_wave reads above are done
    if (lane == 63) s_wave[wave] = xs;
    __syncthreads();
    double woff = 0.0;
    #pragma unroll
    for (int w = 0; w < 4; ++w) if (w < wave) woff += s_wave[w];
    const double excl = woff + (xs - run);   // exclusive prefix of this thread

    // fire detection + weights
    int    fire[8];
    double wmv[8], wlv[8];
    int fcnt = 0;
    double Cprev = excl;
    #pragma unroll
    for (int i = 0; i < 8; ++i) {
        int t = t0 + i;
        double C  = excl + c[i];
        double Dq = floor(C);
        double Dp = floor(Cprev);
        bool f = (Dq != Dp) && (t < xl);
        fire[i] = f ? 1 : 0;
        fcnt += fire[i];
        wmv[i] = f ? (Dq - Cprev) : p[i];
        wlv[i] = f ? (C - Dq) : 0.0;
        Cprev = C;
    }

    // block exclusive scan of fire counts -> global fire index
    int fx = fcnt;
    #pragma unroll
    for (int off = 1; off < 64; off <<= 1) {
        int y = __shfl_up(fx, off, 64);
        if (lane >= off) fx += y;
    }
    if (lane == 63) s_wavei[wave] = fx;
    __syncthreads();
    int ioff = 0;
    #pragma unroll
    for (int w = 0; w < 4; ++w) if (w < wave) ioff += s_wavei[w];
    int k = ioff + (fx - fcnt);              // fires strictly before this thread
    if (tid == 255) out_len[b] = ioff + fx;  // total fires

    // store weights and fire positions
    #pragma unroll
    for (int i = 0; i < 8; ++i) {
        int t = t0 + i;
        wm[b * Tc + t] = (float)wmv[i];
        wl[b * Tc + t] = (float)wlv[i];
        if (fire[i]) { seg_end[b * Tc + k] = t; ++k; }
    }
}

// ---------------- Kernel 2: gather candidate rows + tail ----------------
// grid = (SMAX, B), 128 threads; thread tid covers floats [4*tid, 4*tid+4).
__global__ __launch_bounds__(128) void cif_gather_kernel(
    const f4* __restrict__ x4, const float* __restrict__ wm,
    const float* __restrict__ wl, const int* __restrict__ seg_end,
    const int* __restrict__ out_len, const double* __restrict__ qloss,
    f4* __restrict__ out4, float* __restrict__ out_tail)
{
    const int s    = blockIdx.x;   // 0..SMAX-1
    const int b    = blockIdx.y;
    const int tid  = threadIdx.x;
    const int base = b * Tc;
    const int rs   = Dc / 4;

    f4 acc = {0.f, 0.f, 0.f, 0.f};
    const int ol = out_len[b];
    if (s < ol) {
        const int tEnd = seg_end[base + s];
        const int tBeg = (s == 0) ? 0 : (seg_end[base + s - 1] + 1);
        const f4* xr = x4 + (size_t)base * rs;
        for (int t = tBeg; t <= tEnd; ++t) {
            float w = wm[base + t];
            f4 v = xr[(size_t)t * rs + tid];
            acc += w * v;
        }
        // w_left contribution: previous segment's terminating fire,
        // or (row 0 only) the reference's extra fire[0] add.
        int tl = -1;
        if (s > 0)          tl = tBeg - 1;
        else if (tEnd == 0) tl = 0;        // fire at t==0
        if (tl >= 0) {
            float w = wl[base + tl];
            f4 v = xr[(size_t)tl * rs + tid];
            acc += w * v;
        }
    }
    __builtin_nontemporal_store(acc, &out4[((size_t)(base + s)) * rs + tid]);

    // tail outputs from one block
    if (s == 0 && b == 0) {
        if (tid < Bc) out_tail[tid] = (float)out_len[tid];
        if (tid == Bc) {
            double q = 0.0;
            #pragma unroll
            for (int i = 0; i < Bc; ++i) q += qloss[i];
            out_tail[Bc] = (float)(q / (double)Bc);
        }
    }
}

extern "C" void kernel_launch(void* const* d_in, const int* in_sizes, int n_in,
                              void* d_out, int out_size, void* d_ws, size_t ws_size,
                              hipStream_t stream) {
    const float* x       = (const float*)d_in[0];
    const int*   x_len   = (const int*)d_in[1];
    const float* prob    = (const float*)d_in[2];
    const int*   tgt_len = (const int*)d_in[3];

    float* out = (float*)d_out;

    // workspace layout (8B-aligned first)
    char* ws = (char*)d_ws;
    double* qloss  = (double*)ws;                       // B doubles
    float*  wm     = (float*)(ws + 128);                // B*T floats
    float*  wl     = (float*)(ws + 128 + Bc*Tc*4);      // B*T floats
    int*    segend = (int*)  (ws + 128 + 2*Bc*Tc*4);    // B*T ints
    int*    olen   = (int*)  (ws + 128 + 3*Bc*Tc*4);    // B ints

    cif_scan_kernel<<<Bc + ZBLK, 256, 0, stream>>>(prob, x_len, tgt_len,
                                                   wm, wl, segend, olen, qloss,
                                                   (f4*)out);
    cif_gather_kernel<<<dim3(SMAX, Bc), 128, 0, stream>>>(
        (const f4*)x, wm, wl, segend, olen, qloss,
        (f4*)out, out + (size_t)Bc * Tc * Dc);
}